// Round 12
// baseline (180.860 us; speedup 1.0000x reference)
//
#include <hip/hip_runtime.h>

// Performer (FAVOR+) attention, MI355X, split-bf16 MFMA.
// B=2 H=8 N=8192 D=64 F=256; rows R = 131072.
// Round 12: P-hat stored as SINGLE bf16 (K/Q stay split-bf16) — frees the
// pb_l plane (-32 VGPR held across the loop) and cuts dd GEMMs 3->2 passes.
// Reg model: total/wave at 3 waves/EU ~= 168 (arch+acc); r11 kernels were
// ~188 (124+64); -32 => ~156 => (256,3) legal. ctxK+qoK -> 12 waves/CU.
// Numerics: dd error from P rounding ~2e-3 pre-exp, ~1-2e-4 on out after
// num/den cancellation; expected absmax ~4-6e-4 (revert if validation fails).

typedef __bf16 bf16;
typedef __bf16 bf16x8 __attribute__((ext_vector_type(8)));
typedef _Float16 f16;
typedef f16 f16x8 __attribute__((ext_vector_type(8)));
typedef float f32x4 __attribute__((ext_vector_type(4)));

#define N_    8192
#define BH_   16
#define NRM   0.35355339059327379f   // 64^-0.25
#define RATIO 0.0625f                // 256^-0.5
#define DSC   0.0625f                // 0.5*NRM^2
#define REPS  6.25e-6f               // RATIO*1e-4

#define CTX_W  16
#define KSUM_W (CTX_W + BH_*256*64)     // 262160
#define ZERO_W (KSUM_W + BH_*256)       // 266256

static __device__ __forceinline__ unsigned mapmax(float x){
  unsigned u=__float_as_uint(x); return (u&0x80000000u)? ~u : (u|0x80000000u);
}
static __device__ __forceinline__ float unmapmax(unsigned u){
  return __uint_as_float((u&0x80000000u)? (u&0x7fffffffu) : ~u);
}
static __device__ __forceinline__ f32x4 mfma16(bf16x8 a, bf16x8 b, f32x4 c){
  return __builtin_amdgcn_mfma_f32_16x16x32_bf16(a,b,c,0,0,0);
}
static __device__ __forceinline__ f32x4 mfma16h(f16x8 a, f16x8 b, f32x4 c){
  return __builtin_amdgcn_mfma_f32_16x16x32_f16(a,b,c,0,0,0);
}
static __device__ __forceinline__ void ld8(const float* __restrict__ p, float* x){
  float4 a=*(const float4*)p; float4 b=*(const float4*)(p+4);
  x[0]=a.x; x[1]=a.y; x[2]=a.z; x[3]=a.w; x[4]=b.x; x[5]=b.y; x[6]=b.z; x[7]=b.w;
}
static __device__ __forceinline__ void split8(const float* x, bf16x8& h, bf16x8& l){
  #pragma unroll
  for(int i=0;i<8;++i){ bf16 hi=(bf16)x[i]; h[i]=hi; l[i]=(bf16)(x[i]-(float)hi); }
}
static __device__ __forceinline__ void cvt8b(const float* x, bf16x8& h){
  #pragma unroll
  for(int i=0;i<8;++i) h[i]=(bf16)x[i];
}
static __device__ __forceinline__ void cvt8h(const float* x, f16x8& h){
  #pragma unroll
  for(int i=0;i<8;++i) h[i]=(f16)x[i];
}
static __device__ __forceinline__ void gload16(const float* g, float* l){
  __builtin_amdgcn_global_load_lds(
      (const __attribute__((address_space(1))) unsigned*)g,
      (__attribute__((address_space(3))) unsigned*)l, 16, 0, 0);
}
// P-hat (NRM*P) b-fragments, SINGLE bf16 plane: [ft 0..3][ks 0..1]
static __device__ __forceinline__ void load_P_frags1(const float* __restrict__ Pg,
    int fb, int l15, int g, bf16x8 (&pb)[4][2]){
  #pragma unroll
  for(int ft=0;ft<4;++ft)
    #pragma unroll
    for(int ks=0;ks<2;++ks){
      float x[8]; ld8(&Pg[(fb+16*ft+l15)*64+32*ks+8*g],x);
      #pragma unroll
      for(int i=0;i<8;++i) x[i]*=NRM;
      cvt8b(x,pb[ft][ks]);
    }
}

// stage 32 rows x 64 floats from Xg into LDS buf, source XOR-swizzled by
// row&15 so fragment-pattern b128 reads are conflict-free (r9 pattern).
#define STAGE32(Xg, bufptr, n0s) do{                                      \
    int u0_=tid, u1_=tid+256;                                             \
    int r0_=u0_>>4, c0_=u0_&15, r1_=u1_>>4, c1_=u1_&15;                   \
    gload16((Xg)+((n0s)+r0_)*64+((c0_^(r0_&15))<<2), (bufptr)+u0_*4);     \
    gload16((Xg)+((n0s)+r1_)*64+((c1_^(r1_&15))<<2), (bufptr)+u1_*4);     \
  }while(0)
// x[8] <- staged row rr, k-chunk ks (two swizzled b128 reads)
#define FRAGREAD(xv, bufptr, rr, ksv) do{                                 \
    int cc0_=(8*(ksv)+2*g)^((rr)&15);                                     \
    int cc1_=cc0_^1;                                                      \
    float4 a_=*(const float4*)((bufptr)+(rr)*64+cc0_*4);                  \
    float4 b_=*(const float4*)((bufptr)+(rr)*64+cc1_*4);                  \
    xv[0]=a_.x; xv[1]=a_.y; xv[2]=a_.z; xv[3]=a_.w;                       \
    xv[4]=b_.x; xv[5]=b_.y; xv[6]=b_.z; xv[7]=b_.w;                       \
  }while(0)

// ---------------- kernels ----------------

__global__ void __launch_bounds__(256) initK(unsigned* ws){
  for(int i=blockIdx.x*256+threadIdx.x;i<ZERO_W;i+=gridDim.x*256) ws[i]=0u;
}

// global max of dd_k (single-f16). grid 512, 4 iters of 64 rows (P amortized).
__global__ void __launch_bounds__(256) stabK(const float* __restrict__ Kg,
                                             const float* __restrict__ Pg,
                                             unsigned* __restrict__ stab_ws){
  __shared__ float red[4];
  int tid=threadIdx.x, w=tid>>6, lane=tid&63, l15=lane&15, g=lane>>4;
  int fb=w*64;
  f16x8 pb[4][2];
  #pragma unroll
  for(int ft=0;ft<4;++ft)
    #pragma unroll
    for(int ks=0;ks<2;++ks){
      float x[8]; ld8(&Pg[(fb+16*ft+l15)*64+32*ks+8*g],x);
      #pragma unroll
      for(int i=0;i<8;++i) x[i]*=NRM;
      cvt8h(x,pb[ft][ks]);
    }
  float m=-3.4e38f;
  long base=(long)blockIdx.x*256;
  f32x4 zero={0.f,0.f,0.f,0.f};
  #pragma unroll 1
  for(int it=0;it<4;++it){
    long row0=base+it*64;
    f16x8 ka[4][2];
    #pragma unroll
    for(int rt=0;rt<4;++rt)
      #pragma unroll
      for(int ks=0;ks<2;++ks){
        float x[8]; ld8(&Kg[(row0+16*rt+l15)*64+32*ks+8*g],x);
        cvt8h(x,ka[rt][ks]);
      }
    f32x4 acc[4][4];
    #pragma unroll
    for(int rt=0;rt<4;++rt)
      #pragma unroll
      for(int ft=0;ft<4;++ft) acc[rt][ft]=zero;
    #pragma unroll
    for(int rt=0;rt<4;++rt)
      #pragma unroll
      for(int ft=0;ft<4;++ft)
        #pragma unroll
        for(int ks=0;ks<2;++ks)
          acc[rt][ft]=mfma16h(ka[rt][ks],pb[ft][ks],acc[rt][ft]);
    #pragma unroll
    for(int rt=0;rt<4;++rt)
      #pragma unroll
      for(int ft=0;ft<4;++ft)
        #pragma unroll
        for(int r=0;r<4;++r) m=fmaxf(m,acc[rt][ft][r]);
  }
  #pragma unroll
  for(int off=1;off<64;off<<=1) m=fmaxf(m,__shfl_xor(m,off));
  if(lane==0) red[w]=m;
  __syncthreads();
  if(tid==0){
    m=fmaxf(fmaxf(red[0],red[1]),fmaxf(red[2],red[3]));
    atomicMax(stab_ws,mapmax(m));
  }
}

// kp + ctx/ksum accumulation. grid = 512: 16 bh * 32 chunks of 256 rows,
// 8 iters. K LDS-staged double-buffer; V reg-prefetched; P single bf16;
// dd = (Kh+Kl)@P 2-pass. 3 waves/EU.
__global__ void __launch_bounds__(256,3) ctxK(const float* __restrict__ Kg,
    const float* __restrict__ Vg, const float* __restrict__ Pg,
    const unsigned* __restrict__ stab_ws, float* __restrict__ ctx_g,
    float* __restrict__ ksum_g){
  __shared__ __align__(16) bf16 kpt_h[256*40];   // 20KB
  __shared__ float kstage[2][2048];              // 2 x 8KB staged K tiles
  int tid=threadIdx.x, w=tid>>6, lane=tid&63, l15=lane&15, g=lane>>4;
  int fb=w*64;
  int bh=blockIdx.x>>5, ch=blockIdx.x&31;
  long rowbase=(long)bh*N_ + ch*256;
  float stab=unmapmax(*stab_ws);
  bf16x8 pb[4][2];
  load_P_frags1(Pg,fb,l15,g,pb);
  f32x4 zero={0.f,0.f,0.f,0.f};
  f32x4 cacc[4][4];
  #pragma unroll
  for(int mt=0;mt<4;++mt)
    #pragma unroll
    for(int et=0;et<4;++et) cacc[mt][et]=zero;
  float ksacc[4]={0.f,0.f,0.f,0.f};
  int cur=0;
  STAGE32(Kg, &kstage[0][0], rowbase);
  __syncthreads();                       // drain staging for iter 0
  #pragma unroll 1
  for(int it=0;it<8;++it){
    long n0=rowbase+it*32;
    long np=(it==7)? rowbase : n0+32;    // last iter: dummy re-stage (harmless)
    STAGE32(Kg, &kstage[cur^1][0], np);  // issue next K tile; lands by barrier
    // V raw prefetch (latency hidden under dd-GEMM + exp)
    float vx[4][8];
    #pragma unroll
    for(int et=0;et<4;++et)
      #pragma unroll
      for(int j=0;j<8;++j) vx[et][j]=Vg[(n0+8*g+j)*64+16*et+l15];
    // K a-frags (split) + row sums of squares, from staged LDS
    bf16x8 ka_h[2][2], ka_l[2][2];
    float dsq[2];
    #pragma unroll
    for(int rt=0;rt<2;++rt){
      float ss=0.f;
      #pragma unroll
      for(int ks=0;ks<2;++ks){
        float x[8]; FRAGREAD(x,&kstage[cur][0],16*rt+l15,ks);
        #pragma unroll
        for(int i=0;i<8;++i) ss=fmaf(x[i],x[i],ss);
        split8(x,ka_h[rt][ks],ka_l[rt][ks]);
      }
      ss+=__shfl_xor(ss,16); ss+=__shfl_xor(ss,32);
      dsq[rt]=DSC*ss;
    }
    // dd = (Kh + Kl) @ P (2-pass; P single bf16)
    f32x4 dacc[2][4];
    #pragma unroll
    for(int rt=0;rt<2;++rt)
      #pragma unroll
      for(int ft=0;ft<4;++ft) dacc[rt][ft]=zero;
    #pragma unroll
    for(int rt=0;rt<2;++rt)
      #pragma unroll
      for(int ft=0;ft<4;++ft)
        #pragma unroll
        for(int ks=0;ks<2;++ks){
          dacc[rt][ft]=mfma16(ka_h[rt][ks],pb[ft][ks],dacc[rt][ft]);
          dacc[rt][ft]=mfma16(ka_l[rt][ks],pb[ft][ks],dacc[rt][ft]);
        }
    float dg[2][4];
    #pragma unroll
    for(int rt=0;rt<2;++rt)
      #pragma unroll
      for(int r=0;r<4;++r) dg[rt][r]=__shfl(dsq[rt],4*g+r);
    // kp = RATIO*exp(dd - diag - stab) + REPS, rounded to bf16;
    // ksum accumulates the SAME rounded value (consistent features).
    #pragma unroll
    for(int rt=0;rt<2;++rt)
      #pragma unroll
      for(int ft=0;ft<4;++ft){
        int f=fb+16*ft+l15;
        #pragma unroll
        for(int r=0;r<4;++r){
          float kp=fmaf(RATIO,__expf(dacc[rt][ft][r]-dg[rt][r]-stab),REPS);
          bf16 hb=(bf16)kp;
          ksacc[ft]+=(float)hb;
          int nn=16*rt+4*g+r;
          kpt_h[f*40+nn]=hb;
        }
      }
    // V b-frags (split from prefetched registers)
    bf16x8 vb_h[4], vb_l[4];
    #pragma unroll
    for(int et=0;et<4;++et) split8(vx[et],vb_h[et],vb_l[et]);
    // ctx += kp_b^T @ V (kp single-plane x V split = 2-pass)
    #pragma unroll
    for(int mt=0;mt<4;++mt){
      bf16x8 a_h=*(const bf16x8*)&kpt_h[(fb+16*mt+l15)*40+8*g];
      #pragma unroll
      for(int et=0;et<4;++et){
        cacc[mt][et]=mfma16(a_h,vb_h[et],cacc[mt][et]);
        cacc[mt][et]=mfma16(a_h,vb_l[et],cacc[mt][et]);
      }
    }
    __syncthreads();   // kstage[cur] reads done; staging vmcnt drained
    cur^=1;
  }
  float* cg=ctx_g+(long)bh*16384;
  #pragma unroll
  for(int mt=0;mt<4;++mt)
    #pragma unroll
    for(int et=0;et<4;++et)
      #pragma unroll
      for(int r=0;r<4;++r)
        atomicAdd(&cg[(fb+16*mt+4*g+r)*64+16*et+l15],cacc[mt][et][r]);
  #pragma unroll
  for(int ft=0;ft<4;++ft){
    float s=ksacc[ft];
    s+=__shfl_xor(s,16); s+=__shfl_xor(s,32);
    if(g==0) atomicAdd(&ksum_g[bh*256+fb+16*ft+l15],s);
  }
}

// fused qp + out. grid = 512: 16 bh * 32 chunks of 256 rows, 8 iters.
// Q LDS-staged double-buffer; P single bf16 (2-pass dd); qp single-bf16
// direct ds_write_b16. 3 waves/EU.
__global__ void __launch_bounds__(256,3) qoK(const float* __restrict__ Qg,
    const float* __restrict__ Pg, const float* __restrict__ ctx_g,
    const float* __restrict__ ksum_g, float* __restrict__ outg){
  __shared__ float qstage[2][2048];          // 2 x 8KB staged Q tiles (swizzled)
  __shared__ __align__(16) bf16 qpt[32*264]; // bf16 qp plane, [n][f], stride 264
  __shared__ float rmaxl[4][32];
  __shared__ float denl[4][32];
  int tid=threadIdx.x, w=tid>>6, lane=tid&63, l15=lane&15, g=lane>>4;
  int fb=w*64;
  int bh=blockIdx.x>>5, ch=blockIdx.x&31;
  long rowbase=(long)bh*N_ + ch*256;

  bf16x8 pb[4][2];
  load_P_frags1(Pg,fb,l15,g,pb);
  float ksv[4];
  #pragma unroll
  for(int ft=0;ft<4;++ft) ksv[ft]=ksum_g[bh*256+fb+16*ft+l15];
  // ctx b-frags for this wave's e-tile (et = w), split
  bf16x8 cb_h[8], cb_l[8];
  #pragma unroll
  for(int ks=0;ks<8;++ks){
    float x[8];
    #pragma unroll
    for(int j=0;j<8;++j) x[j]=ctx_g[(long)bh*16384+(32*ks+8*g+j)*64+16*w+l15];
    split8(x,cb_h[ks],cb_l[ks]);
  }
  f32x4 zero={0.f,0.f,0.f,0.f};
  int cur=0;
  STAGE32(Qg, &qstage[0][0], rowbase);
  __syncthreads();                     // drain staging for iter 0
  #pragma unroll 1
  for(int it=0;it<8;++it){
    long n0=rowbase+it*32;
    long np=(it==7)? rowbase : n0+32;  // last iter: dummy re-stage (harmless)
    STAGE32(Qg, &qstage[cur^1][0], np);// issue next tile; lands by next barrier
    // Q a-frags (split) + diag from staged LDS
    bf16x8 qa_h[2][2], qa_l[2][2];
    float dsq[2];
    #pragma unroll
    for(int rt=0;rt<2;++rt){
      float ss=0.f;
      #pragma unroll
      for(int ks=0;ks<2;++ks){
        float x[8]; FRAGREAD(x,&qstage[cur][0],16*rt+l15,ks);
        #pragma unroll
        for(int i=0;i<8;++i) ss=fmaf(x[i],x[i],ss);
        split8(x,qa_h[rt][ks],qa_l[rt][ks]);
      }
      ss+=__shfl_xor(ss,16); ss+=__shfl_xor(ss,32);
      dsq[rt]=DSC*ss;
    }
    // dd = (Qh + Ql) @ P (2-pass; P single bf16)
    f32x4 dacc[2][4];
    #pragma unroll
    for(int rt=0;rt<2;++rt)
      #pragma unroll
      for(int ft=0;ft<4;++ft) dacc[rt][ft]=zero;
    #pragma unroll
    for(int rt=0;rt<2;++rt)
      #pragma unroll
      for(int ft=0;ft<4;++ft)
        #pragma unroll
        for(int ks=0;ks<2;++ks){
          dacc[rt][ft]=mfma16(qa_h[rt][ks],pb[ft][ks],dacc[rt][ft]);
          dacc[rt][ft]=mfma16(qa_l[rt][ks],pb[ft][ks],dacc[rt][ft]);
        }
    float dg[2][4];
    #pragma unroll
    for(int rt=0;rt<2;++rt)
      #pragma unroll
      for(int r=0;r<4;++r) dg[rt][r]=__shfl(dsq[rt],4*g+r);
    // per-wave rowmax over its f-strip
    #pragma unroll
    for(int rt=0;rt<2;++rt)
      #pragma unroll
      for(int r=0;r<4;++r){
        float m=fmaxf(fmaxf(dacc[rt][0][r],dacc[rt][1][r]),
                      fmaxf(dacc[rt][2][r],dacc[rt][3][r]));
        m=fmaxf(m,__shfl_xor(m,1)); m=fmaxf(m,__shfl_xor(m,2));
        m=fmaxf(m,__shfl_xor(m,4)); m=fmaxf(m,__shfl_xor(m,8));
        if(l15==0) rmaxl[w][16*rt+4*g+r]=m;
      }
    __syncthreads();   // rowmax planes ready (also fences staging of cur^1)
    // qp (rounded bf16), den partials from the SAME rounded value,
    // direct b16 writes into qpt[n][f]
    #pragma unroll
    for(int rt=0;rt<2;++rt)
      #pragma unroll
      for(int r=0;r<4;++r){
        int nn=16*rt+4*g+r;
        float rm=fmaxf(fmaxf(rmaxl[0][nn],rmaxl[1][nn]),
                       fmaxf(rmaxl[2][nn],rmaxl[3][nn]));
        float dp=0.f;
        #pragma unroll
        for(int ft=0;ft<4;++ft){
          float qp=fmaf(RATIO,__expf(dacc[rt][ft][r]-dg[rt][r]-rm),REPS);
          bf16 hb=(bf16)qp;
          dp=fmaf((float)hb,ksv[ft],dp);
          qpt[nn*264 + fb+16*ft+l15]=hb;
        }
        dp+=__shfl_xor(dp,1); dp+=__shfl_xor(dp,2);
        dp+=__shfl_xor(dp,4); dp+=__shfl_xor(dp,8);
        if(l15==0) denl[w][nn]=dp;
      }
    __syncthreads();   // qpt + denl ready
    // out = qp_b @ ctx (single-plane qp x split ctx = 2-pass)
    f32x4 oacc[2]; oacc[0]=zero; oacc[1]=zero;
    #pragma unroll
    for(int ks=0;ks<8;++ks)
      #pragma unroll
      for(int mt=0;mt<2;++mt){
        bf16x8 a_h=*(const bf16x8*)&qpt[(16*mt+l15)*264+32*ks+8*g];
        oacc[mt]=mfma16(a_h,cb_h[ks],oacc[mt]);
        oacc[mt]=mfma16(a_h,cb_l[ks],oacc[mt]);
      }
    #pragma unroll
    for(int mt=0;mt<2;++mt)
      #pragma unroll
      for(int r=0;r<4;++r){
        int nn=16*mt+4*g+r;
        float den=denl[0][nn]+denl[1][nn]+denl[2][nn]+denl[3][nn];
        outg[(n0+nn)*64+16*w+l15]=oacc[mt][r]/den;
      }
    cur^=1;
  }
}

// ---------------- host ----------------

extern "C" void kernel_launch(void* const* d_in, const int* in_sizes, int n_in,
                              void* d_out, int out_size, void* d_ws, size_t ws_size,
                              hipStream_t stream) {
  (void)in_sizes; (void)n_in; (void)out_size; (void)ws_size;
  const float* q = (const float*)d_in[0];
  const float* k = (const float*)d_in[1];
  const float* v = (const float*)d_in[2];
  const float* P = (const float*)d_in[3];
  float* out = (float*)d_out;

  unsigned* stab = (unsigned*)d_ws;
  float* ctx  = (float*)d_ws + CTX_W;
  float* ksum = (float*)d_ws + KSUM_W;

  hipLaunchKernelGGL(initK, dim3(256), dim3(256), 0, stream, (unsigned*)d_ws);
  hipLaunchKernelGGL(stabK, dim3(512), dim3(256), 0, stream, k, P, stab);
  hipLaunchKernelGGL(ctxK, dim3(512), dim3(256), 0, stream, k, v, P, stab, ctx, ksum);
  hipLaunchKernelGGL(qoK, dim3(512), dim3(256), 0, stream, q, P, ctx, ksum, out);
}

// Round 13
// 146.878 us; speedup vs baseline: 1.2314x; 1.2314x over previous
//
#include <hip/hip_runtime.h>

// Performer (FAVOR+) attention, MI355X, split-bf16 MFMA.
// B=2 H=8 N=8192 D=64 F=256; rows R = 131072.
// Round 13: consolidate. (256,3) is permanently closed for this structure
// (4 spill failures r4/r7/r10/r12 — compiler temporaries put true demand
// ~200+ vs the ~168 cap). Revert ctxK/qoK to (256,2) (r11 codegen), KEEP
// single-bf16 P-hat + 2-pass dd (r12-validated: absmax bit-identical
// 2.441e-4) in both kernels. K/Q staged via gload_lds dbuf; V reg-prefetch.

typedef __bf16 bf16;
typedef __bf16 bf16x8 __attribute__((ext_vector_type(8)));
typedef _Float16 f16;
typedef f16 f16x8 __attribute__((ext_vector_type(8)));
typedef float f32x4 __attribute__((ext_vector_type(4)));

#define N_    8192
#define BH_   16
#define NRM   0.35355339059327379f   // 64^-0.25
#define RATIO 0.0625f                // 256^-0.5
#define DSC   0.0625f                // 0.5*NRM^2
#define REPS  6.25e-6f               // RATIO*1e-4

#define CTX_W  16
#define KSUM_W (CTX_W + BH_*256*64)     // 262160
#define ZERO_W (KSUM_W + BH_*256)       // 266256

static __device__ __forceinline__ unsigned mapmax(float x){
  unsigned u=__float_as_uint(x); return (u&0x80000000u)? ~u : (u|0x80000000u);
}
static __device__ __forceinline__ float unmapmax(unsigned u){
  return __uint_as_float((u&0x80000000u)? (u&0x7fffffffu) : ~u);
}
static __device__ __forceinline__ f32x4 mfma16(bf16x8 a, bf16x8 b, f32x4 c){
  return __builtin_amdgcn_mfma_f32_16x16x32_bf16(a,b,c,0,0,0);
}
static __device__ __forceinline__ f32x4 mfma16h(f16x8 a, f16x8 b, f32x4 c){
  return __builtin_amdgcn_mfma_f32_16x16x32_f16(a,b,c,0,0,0);
}
static __device__ __forceinline__ void ld8(const float* __restrict__ p, float* x){
  float4 a=*(const float4*)p; float4 b=*(const float4*)(p+4);
  x[0]=a.x; x[1]=a.y; x[2]=a.z; x[3]=a.w; x[4]=b.x; x[5]=b.y; x[6]=b.z; x[7]=b.w;
}
static __device__ __forceinline__ void split8(const float* x, bf16x8& h, bf16x8& l){
  #pragma unroll
  for(int i=0;i<8;++i){ bf16 hi=(bf16)x[i]; h[i]=hi; l[i]=(bf16)(x[i]-(float)hi); }
}
static __device__ __forceinline__ void cvt8b(const float* x, bf16x8& h){
  #pragma unroll
  for(int i=0;i<8;++i) h[i]=(bf16)x[i];
}
static __device__ __forceinline__ void cvt8h(const float* x, f16x8& h){
  #pragma unroll
  for(int i=0;i<8;++i) h[i]=(f16)x[i];
}
static __device__ __forceinline__ void gload16(const float* g, float* l){
  __builtin_amdgcn_global_load_lds(
      (const __attribute__((address_space(1))) unsigned*)g,
      (__attribute__((address_space(3))) unsigned*)l, 16, 0, 0);
}
// P-hat (NRM*P) b-fragments, SINGLE bf16 plane: [ft 0..3][ks 0..1]
static __device__ __forceinline__ void load_P_frags1(const float* __restrict__ Pg,
    int fb, int l15, int g, bf16x8 (&pb)[4][2]){
  #pragma unroll
  for(int ft=0;ft<4;++ft)
    #pragma unroll
    for(int ks=0;ks<2;++ks){
      float x[8]; ld8(&Pg[(fb+16*ft+l15)*64+32*ks+8*g],x);
      #pragma unroll
      for(int i=0;i<8;++i) x[i]*=NRM;
      cvt8b(x,pb[ft][ks]);
    }
}

// stage 32 rows x 64 floats from Xg into LDS buf, source XOR-swizzled by
// row&15 so fragment-pattern b128 reads are conflict-free (r9 pattern).
#define STAGE32(Xg, bufptr, n0s) do{                                      \
    int u0_=tid, u1_=tid+256;                                             \
    int r0_=u0_>>4, c0_=u0_&15, r1_=u1_>>4, c1_=u1_&15;                   \
    gload16((Xg)+((n0s)+r0_)*64+((c0_^(r0_&15))<<2), (bufptr)+u0_*4);     \
    gload16((Xg)+((n0s)+r1_)*64+((c1_^(r1_&15))<<2), (bufptr)+u1_*4);     \
  }while(0)
// x[8] <- staged row rr, k-chunk ks (two swizzled b128 reads)
#define FRAGREAD(xv, bufptr, rr, ksv) do{                                 \
    int cc0_=(8*(ksv)+2*g)^((rr)&15);                                     \
    int cc1_=cc0_^1;                                                      \
    float4 a_=*(const float4*)((bufptr)+(rr)*64+cc0_*4);                  \
    float4 b_=*(const float4*)((bufptr)+(rr)*64+cc1_*4);                  \
    xv[0]=a_.x; xv[1]=a_.y; xv[2]=a_.z; xv[3]=a_.w;                       \
    xv[4]=b_.x; xv[5]=b_.y; xv[6]=b_.z; xv[7]=b_.w;                       \
  }while(0)

// ---------------- kernels ----------------

__global__ void __launch_bounds__(256) initK(unsigned* ws){
  for(int i=blockIdx.x*256+threadIdx.x;i<ZERO_W;i+=gridDim.x*256) ws[i]=0u;
}

// global max of dd_k (single-f16). grid 512, 4 iters of 64 rows (P amortized).
__global__ void __launch_bounds__(256) stabK(const float* __restrict__ Kg,
                                             const float* __restrict__ Pg,
                                             unsigned* __restrict__ stab_ws){
  __shared__ float red[4];
  int tid=threadIdx.x, w=tid>>6, lane=tid&63, l15=lane&15, g=lane>>4;
  int fb=w*64;
  f16x8 pb[4][2];
  #pragma unroll
  for(int ft=0;ft<4;++ft)
    #pragma unroll
    for(int ks=0;ks<2;++ks){
      float x[8]; ld8(&Pg[(fb+16*ft+l15)*64+32*ks+8*g],x);
      #pragma unroll
      for(int i=0;i<8;++i) x[i]*=NRM;
      cvt8h(x,pb[ft][ks]);
    }
  float m=-3.4e38f;
  long base=(long)blockIdx.x*256;
  f32x4 zero={0.f,0.f,0.f,0.f};
  #pragma unroll 1
  for(int it=0;it<4;++it){
    long row0=base+it*64;
    f16x8 ka[4][2];
    #pragma unroll
    for(int rt=0;rt<4;++rt)
      #pragma unroll
      for(int ks=0;ks<2;++ks){
        float x[8]; ld8(&Kg[(row0+16*rt+l15)*64+32*ks+8*g],x);
        cvt8h(x,ka[rt][ks]);
      }
    f32x4 acc[4][4];
    #pragma unroll
    for(int rt=0;rt<4;++rt)
      #pragma unroll
      for(int ft=0;ft<4;++ft) acc[rt][ft]=zero;
    #pragma unroll
    for(int rt=0;rt<4;++rt)
      #pragma unroll
      for(int ft=0;ft<4;++ft)
        #pragma unroll
        for(int ks=0;ks<2;++ks)
          acc[rt][ft]=mfma16h(ka[rt][ks],pb[ft][ks],acc[rt][ft]);
    #pragma unroll
    for(int rt=0;rt<4;++rt)
      #pragma unroll
      for(int ft=0;ft<4;++ft)
        #pragma unroll
        for(int r=0;r<4;++r) m=fmaxf(m,acc[rt][ft][r]);
  }
  #pragma unroll
  for(int off=1;off<64;off<<=1) m=fmaxf(m,__shfl_xor(m,off));
  if(lane==0) red[w]=m;
  __syncthreads();
  if(tid==0){
    m=fmaxf(fmaxf(red[0],red[1]),fmaxf(red[2],red[3]));
    atomicMax(stab_ws,mapmax(m));
  }
}

// kp + ctx/ksum accumulation. grid = 512: 16 bh * 32 chunks of 256 rows,
// 8 iters. K LDS-staged double-buffer; V reg-prefetched; P single bf16;
// dd = (Kh+Kl)@P 2-pass. 2 waves/EU (proven config).
__global__ void __launch_bounds__(256,2) ctxK(const float* __restrict__ Kg,
    const float* __restrict__ Vg, const float* __restrict__ Pg,
    const unsigned* __restrict__ stab_ws, float* __restrict__ ctx_g,
    float* __restrict__ ksum_g){
  __shared__ __align__(16) bf16 kpt_h[256*40];   // 20KB
  __shared__ float kstage[2][2048];              // 2 x 8KB staged K tiles
  int tid=threadIdx.x, w=tid>>6, lane=tid&63, l15=lane&15, g=lane>>4;
  int fb=w*64;
  int bh=blockIdx.x>>5, ch=blockIdx.x&31;
  long rowbase=(long)bh*N_ + ch*256;
  float stab=unmapmax(*stab_ws);
  bf16x8 pb[4][2];
  load_P_frags1(Pg,fb,l15,g,pb);
  f32x4 zero={0.f,0.f,0.f,0.f};
  f32x4 cacc[4][4];
  #pragma unroll
  for(int mt=0;mt<4;++mt)
    #pragma unroll
    for(int et=0;et<4;++et) cacc[mt][et]=zero;
  float ksacc[4]={0.f,0.f,0.f,0.f};
  int cur=0;
  STAGE32(Kg, &kstage[0][0], rowbase);
  __syncthreads();                       // drain staging for iter 0
  #pragma unroll 1
  for(int it=0;it<8;++it){
    long n0=rowbase+it*32;
    long np=(it==7)? rowbase : n0+32;    // last iter: dummy re-stage (harmless)
    STAGE32(Kg, &kstage[cur^1][0], np);  // issue next K tile; lands by barrier
    // V raw prefetch (latency hidden under dd-GEMM + exp)
    float vx[4][8];
    #pragma unroll
    for(int et=0;et<4;++et)
      #pragma unroll
      for(int j=0;j<8;++j) vx[et][j]=Vg[(n0+8*g+j)*64+16*et+l15];
    // K a-frags (split) + row sums of squares, from staged LDS
    bf16x8 ka_h[2][2], ka_l[2][2];
    float dsq[2];
    #pragma unroll
    for(int rt=0;rt<2;++rt){
      float ss=0.f;
      #pragma unroll
      for(int ks=0;ks<2;++ks){
        float x[8]; FRAGREAD(x,&kstage[cur][0],16*rt+l15,ks);
        #pragma unroll
        for(int i=0;i<8;++i) ss=fmaf(x[i],x[i],ss);
        split8(x,ka_h[rt][ks],ka_l[rt][ks]);
      }
      ss+=__shfl_xor(ss,16); ss+=__shfl_xor(ss,32);
      dsq[rt]=DSC*ss;
    }
    // dd = (Kh + Kl) @ P (2-pass; P single bf16)
    f32x4 dacc[2][4];
    #pragma unroll
    for(int rt=0;rt<2;++rt)
      #pragma unroll
      for(int ft=0;ft<4;++ft) dacc[rt][ft]=zero;
    #pragma unroll
    for(int rt=0;rt<2;++rt)
      #pragma unroll
      for(int ft=0;ft<4;++ft)
        #pragma unroll
        for(int ks=0;ks<2;++ks){
          dacc[rt][ft]=mfma16(ka_h[rt][ks],pb[ft][ks],dacc[rt][ft]);
          dacc[rt][ft]=mfma16(ka_l[rt][ks],pb[ft][ks],dacc[rt][ft]);
        }
    float dg[2][4];
    #pragma unroll
    for(int rt=0;rt<2;++rt)
      #pragma unroll
      for(int r=0;r<4;++r) dg[rt][r]=__shfl(dsq[rt],4*g+r);
    // kp = RATIO*exp(dd - diag - stab) + REPS, rounded to bf16;
    // ksum accumulates the SAME rounded value (consistent features).
    #pragma unroll
    for(int rt=0;rt<2;++rt)
      #pragma unroll
      for(int ft=0;ft<4;++ft){
        int f=fb+16*ft+l15;
        #pragma unroll
        for(int r=0;r<4;++r){
          float kp=fmaf(RATIO,__expf(dacc[rt][ft][r]-dg[rt][r]-stab),REPS);
          bf16 hb=(bf16)kp;
          ksacc[ft]+=(float)hb;
          int nn=16*rt+4*g+r;
          kpt_h[f*40+nn]=hb;
        }
      }
    // V b-frags (split from prefetched registers)
    bf16x8 vb_h[4], vb_l[4];
    #pragma unroll
    for(int et=0;et<4;++et) split8(vx[et],vb_h[et],vb_l[et]);
    // ctx += kp_b^T @ V (kp single-plane x V split = 2-pass)
    #pragma unroll
    for(int mt=0;mt<4;++mt){
      bf16x8 a_h=*(const bf16x8*)&kpt_h[(fb+16*mt+l15)*40+8*g];
      #pragma unroll
      for(int et=0;et<4;++et){
        cacc[mt][et]=mfma16(a_h,vb_h[et],cacc[mt][et]);
        cacc[mt][et]=mfma16(a_h,vb_l[et],cacc[mt][et]);
      }
    }
    __syncthreads();   // kstage[cur] reads done; staging vmcnt drained
    cur^=1;
  }
  float* cg=ctx_g+(long)bh*16384;
  #pragma unroll
  for(int mt=0;mt<4;++mt)
    #pragma unroll
    for(int et=0;et<4;++et)
      #pragma unroll
      for(int r=0;r<4;++r)
        atomicAdd(&cg[(fb+16*mt+4*g+r)*64+16*et+l15],cacc[mt][et][r]);
  #pragma unroll
  for(int ft=0;ft<4;++ft){
    float s=ksacc[ft];
    s+=__shfl_xor(s,16); s+=__shfl_xor(s,32);
    if(g==0) atomicAdd(&ksum_g[bh*256+fb+16*ft+l15],s);
  }
}

// fused qp + out. grid = 512: 16 bh * 32 chunks of 256 rows, 8 iters.
// Q LDS-staged double-buffer; P single bf16 (2-pass dd); qp single-bf16
// direct ds_write_b16. 2 waves/EU (proven config).
__global__ void __launch_bounds__(256,2) qoK(const float* __restrict__ Qg,
    const float* __restrict__ Pg, const float* __restrict__ ctx_g,
    const float* __restrict__ ksum_g, float* __restrict__ outg){
  __shared__ float qstage[2][2048];          // 2 x 8KB staged Q tiles (swizzled)
  __shared__ __align__(16) bf16 qpt[32*264]; // bf16 qp plane, [n][f], stride 264
  __shared__ float rmaxl[4][32];
  __shared__ float denl[4][32];
  int tid=threadIdx.x, w=tid>>6, lane=tid&63, l15=lane&15, g=lane>>4;
  int fb=w*64;
  int bh=blockIdx.x>>5, ch=blockIdx.x&31;
  long rowbase=(long)bh*N_ + ch*256;

  bf16x8 pb[4][2];
  load_P_frags1(Pg,fb,l15,g,pb);
  float ksv[4];
  #pragma unroll
  for(int ft=0;ft<4;++ft) ksv[ft]=ksum_g[bh*256+fb+16*ft+l15];
  // ctx b-frags for this wave's e-tile (et = w), split
  bf16x8 cb_h[8], cb_l[8];
  #pragma unroll
  for(int ks=0;ks<8;++ks){
    float x[8];
    #pragma unroll
    for(int j=0;j<8;++j) x[j]=ctx_g[(long)bh*16384+(32*ks+8*g+j)*64+16*w+l15];
    split8(x,cb_h[ks],cb_l[ks]);
  }
  f32x4 zero={0.f,0.f,0.f,0.f};
  int cur=0;
  STAGE32(Qg, &qstage[0][0], rowbase);
  __syncthreads();                     // drain staging for iter 0
  #pragma unroll 1
  for(int it=0;it<8;++it){
    long n0=rowbase+it*32;
    long np=(it==7)? rowbase : n0+32;  // last iter: dummy re-stage (harmless)
    STAGE32(Qg, &qstage[cur^1][0], np);// issue next tile; lands by next barrier
    // Q a-frags (split) + diag from staged LDS
    bf16x8 qa_h[2][2], qa_l[2][2];
    float dsq[2];
    #pragma unroll
    for(int rt=0;rt<2;++rt){
      float ss=0.f;
      #pragma unroll
      for(int ks=0;ks<2;++ks){
        float x[8]; FRAGREAD(x,&qstage[cur][0],16*rt+l15,ks);
        #pragma unroll
        for(int i=0;i<8;++i) ss=fmaf(x[i],x[i],ss);
        split8(x,qa_h[rt][ks],qa_l[rt][ks]);
      }
      ss+=__shfl_xor(ss,16); ss+=__shfl_xor(ss,32);
      dsq[rt]=DSC*ss;
    }
    // dd = (Qh + Ql) @ P (2-pass; P single bf16)
    f32x4 dacc[2][4];
    #pragma unroll
    for(int rt=0;rt<2;++rt)
      #pragma unroll
      for(int ft=0;ft<4;++ft) dacc[rt][ft]=zero;
    #pragma unroll
    for(int rt=0;rt<2;++rt)
      #pragma unroll
      for(int ft=0;ft<4;++ft)
        #pragma unroll
        for(int ks=0;ks<2;++ks){
          dacc[rt][ft]=mfma16(qa_h[rt][ks],pb[ft][ks],dacc[rt][ft]);
          dacc[rt][ft]=mfma16(qa_l[rt][ks],pb[ft][ks],dacc[rt][ft]);
        }
    float dg[2][4];
    #pragma unroll
    for(int rt=0;rt<2;++rt)
      #pragma unroll
      for(int r=0;r<4;++r) dg[rt][r]=__shfl(dsq[rt],4*g+r);
    // per-wave rowmax over its f-strip
    #pragma unroll
    for(int rt=0;rt<2;++rt)
      #pragma unroll
      for(int r=0;r<4;++r){
        float m=fmaxf(fmaxf(dacc[rt][0][r],dacc[rt][1][r]),
                      fmaxf(dacc[rt][2][r],dacc[rt][3][r]));
        m=fmaxf(m,__shfl_xor(m,1)); m=fmaxf(m,__shfl_xor(m,2));
        m=fmaxf(m,__shfl_xor(m,4)); m=fmaxf(m,__shfl_xor(m,8));
        if(l15==0) rmaxl[w][16*rt+4*g+r]=m;
      }
    __syncthreads();   // rowmax planes ready (also fences staging of cur^1)
    // qp (rounded bf16), den partials from the SAME rounded value,
    // direct b16 writes into qpt[n][f]
    #pragma unroll
    for(int rt=0;rt<2;++rt)
      #pragma unroll
      for(int r=0;r<4;++r){
        int nn=16*rt+4*g+r;
        float rm=fmaxf(fmaxf(rmaxl[0][nn],rmaxl[1][nn]),
                       fmaxf(rmaxl[2][nn],rmaxl[3][nn]));
        float dp=0.f;
        #pragma unroll
        for(int ft=0;ft<4;++ft){
          float qp=fmaf(RATIO,__expf(dacc[rt][ft][r]-dg[rt][r]-rm),REPS);
          bf16 hb=(bf16)qp;
          dp=fmaf((float)hb,ksv[ft],dp);
          qpt[nn*264 + fb+16*ft+l15]=hb;
        }
        dp+=__shfl_xor(dp,1); dp+=__shfl_xor(dp,2);
        dp+=__shfl_xor(dp,4); dp+=__shfl_xor(dp,8);
        if(l15==0) denl[w][nn]=dp;
      }
    __syncthreads();   // qpt + denl ready
    // out = qp_b @ ctx (single-plane qp x split ctx = 2-pass)
    f32x4 oacc[2]; oacc[0]=zero; oacc[1]=zero;
    #pragma unroll
    for(int ks=0;ks<8;++ks)
      #pragma unroll
      for(int mt=0;mt<2;++mt){
        bf16x8 a_h=*(const bf16x8*)&qpt[(16*mt+l15)*264+32*ks+8*g];
        oacc[mt]=mfma16(a_h,cb_h[ks],oacc[mt]);
        oacc[mt]=mfma16(a_h,cb_l[ks],oacc[mt]);
      }
    #pragma unroll
    for(int mt=0;mt<2;++mt)
      #pragma unroll
      for(int r=0;r<4;++r){
        int nn=16*mt+4*g+r;
        float den=denl[0][nn]+denl[1][nn]+denl[2][nn]+denl[3][nn];
        outg[(n0+nn)*64+16*w+l15]=oacc[mt][r]/den;
      }
    cur^=1;
  }
}

// ---------------- host ----------------

extern "C" void kernel_launch(void* const* d_in, const int* in_sizes, int n_in,
                              void* d_out, int out_size, void* d_ws, size_t ws_size,
                              hipStream_t stream) {
  (void)in_sizes; (void)n_in; (void)out_size; (void)ws_size;
  const float* q = (const float*)d_in[0];
  const float* k = (const float*)d_in[1];
  const float* v = (const float*)d_in[2];
  const float* P = (const float*)d_in[3];
  float* out = (float*)d_out;

  unsigned* stab = (unsigned*)d_ws;
  float* ctx  = (float*)d_ws + CTX_W;
  float* ksum = (float*)d_ws + KSUM_W;

  hipLaunchKernelGGL(initK, dim3(256), dim3(256), 0, stream, (unsigned*)d_ws);
  hipLaunchKernelGGL(stabK, dim3(512), dim3(256), 0, stream, k, P, stab);
  hipLaunchKernelGGL(ctxK, dim3(512), dim3(256), 0, stream, k, v, P, stab, ctx, ksum);
  hipLaunchKernelGGL(qoK, dim3(512), dim3(256), 0, stream, q, P, ctx, ksum, out);
}

// Round 14
// 129.398 us; speedup vs baseline: 1.3977x; 1.1351x over previous
//
#include <hip/hip_runtime.h>

// Performer (FAVOR+) attention, MI355X, split-bf16 MFMA.
// B=2 H=8 N=8192 D=64 F=256; rows R = 131072.
// Round 14: two-stage ctx/ksum reduction. Ledger arithmetic (r5: +8.4M
// atomics = +28us) says ctxK's fp32-atomic epilogue (8.4M atomics, 32-way
// contention) costs ~25us of its 65us. Replace with: each (bh,ch) block
// plain-stores its partial ctx+ksum into a private ws slice (32 slices/bh,
// no contention, no init), then redK sums the 32 slices (34MB read, ~9us).
// Runtime ws_size guard: falls back to the r13 atomic path if ws < ~35MB.
// stabK/qoK unchanged from r13.

typedef __bf16 bf16;
typedef __bf16 bf16x8 __attribute__((ext_vector_type(8)));
typedef _Float16 f16;
typedef f16 f16x8 __attribute__((ext_vector_type(8)));
typedef float f32x4 __attribute__((ext_vector_type(4)));

#define N_    8192
#define BH_   16
#define NRM   0.35355339059327379f   // 64^-0.25
#define RATIO 0.0625f                // 256^-0.5
#define DSC   0.0625f                // 0.5*NRM^2
#define REPS  6.25e-6f               // RATIO*1e-4

#define CTX_W  16
#define KSUM_W (CTX_W + BH_*256*64)     // 262160
#define ZERO_W (KSUM_W + BH_*256)       // 266256
#define SLICE_W 16640                   // 16384 ctx + 256 ksum per (bh,ch)
#define PART_W  ZERO_W                  // partials start here (32*16*16640 w)

static __device__ __forceinline__ unsigned mapmax(float x){
  unsigned u=__float_as_uint(x); return (u&0x80000000u)? ~u : (u|0x80000000u);
}
static __device__ __forceinline__ float unmapmax(unsigned u){
  return __uint_as_float((u&0x80000000u)? (u&0x7fffffffu) : ~u);
}
static __device__ __forceinline__ f32x4 mfma16(bf16x8 a, bf16x8 b, f32x4 c){
  return __builtin_amdgcn_mfma_f32_16x16x32_bf16(a,b,c,0,0,0);
}
static __device__ __forceinline__ f32x4 mfma16h(f16x8 a, f16x8 b, f32x4 c){
  return __builtin_amdgcn_mfma_f32_16x16x32_f16(a,b,c,0,0,0);
}
static __device__ __forceinline__ void ld8(const float* __restrict__ p, float* x){
  float4 a=*(const float4*)p; float4 b=*(const float4*)(p+4);
  x[0]=a.x; x[1]=a.y; x[2]=a.z; x[3]=a.w; x[4]=b.x; x[5]=b.y; x[6]=b.z; x[7]=b.w;
}
static __device__ __forceinline__ void split8(const float* x, bf16x8& h, bf16x8& l){
  #pragma unroll
  for(int i=0;i<8;++i){ bf16 hi=(bf16)x[i]; h[i]=hi; l[i]=(bf16)(x[i]-(float)hi); }
}
static __device__ __forceinline__ void cvt8b(const float* x, bf16x8& h){
  #pragma unroll
  for(int i=0;i<8;++i) h[i]=(bf16)x[i];
}
static __device__ __forceinline__ void cvt8h(const float* x, f16x8& h){
  #pragma unroll
  for(int i=0;i<8;++i) h[i]=(f16)x[i];
}
static __device__ __forceinline__ void gload16(const float* g, float* l){
  __builtin_amdgcn_global_load_lds(
      (const __attribute__((address_space(1))) unsigned*)g,
      (__attribute__((address_space(3))) unsigned*)l, 16, 0, 0);
}
// P-hat (NRM*P) b-fragments, SINGLE bf16 plane: [ft 0..3][ks 0..1]
static __device__ __forceinline__ void load_P_frags1(const float* __restrict__ Pg,
    int fb, int l15, int g, bf16x8 (&pb)[4][2]){
  #pragma unroll
  for(int ft=0;ft<4;++ft)
    #pragma unroll
    for(int ks=0;ks<2;++ks){
      float x[8]; ld8(&Pg[(fb+16*ft+l15)*64+32*ks+8*g],x);
      #pragma unroll
      for(int i=0;i<8;++i) x[i]*=NRM;
      cvt8b(x,pb[ft][ks]);
    }
}

// stage 32 rows x 64 floats from Xg into LDS buf, source XOR-swizzled by
// row&15 so fragment-pattern b128 reads are conflict-free (r9 pattern).
#define STAGE32(Xg, bufptr, n0s) do{                                      \
    int u0_=tid, u1_=tid+256;                                             \
    int r0_=u0_>>4, c0_=u0_&15, r1_=u1_>>4, c1_=u1_&15;                   \
    gload16((Xg)+((n0s)+r0_)*64+((c0_^(r0_&15))<<2), (bufptr)+u0_*4);     \
    gload16((Xg)+((n0s)+r1_)*64+((c1_^(r1_&15))<<2), (bufptr)+u1_*4);     \
  }while(0)
// x[8] <- staged row rr, k-chunk ks (two swizzled b128 reads)
#define FRAGREAD(xv, bufptr, rr, ksv) do{                                 \
    int cc0_=(8*(ksv)+2*g)^((rr)&15);                                     \
    int cc1_=cc0_^1;                                                      \
    float4 a_=*(const float4*)((bufptr)+(rr)*64+cc0_*4);                  \
    float4 b_=*(const float4*)((bufptr)+(rr)*64+cc1_*4);                  \
    xv[0]=a_.x; xv[1]=a_.y; xv[2]=a_.z; xv[3]=a_.w;                       \
    xv[4]=b_.x; xv[5]=b_.y; xv[6]=b_.z; xv[7]=b_.w;                       \
  }while(0)

// ---------------- kernels ----------------

__global__ void __launch_bounds__(256) initK(unsigned* ws){
  for(int i=blockIdx.x*256+threadIdx.x;i<ZERO_W;i+=gridDim.x*256) ws[i]=0u;
}

// global max of dd_k (single-f16). grid 512, 4 iters of 64 rows (P amortized).
__global__ void __launch_bounds__(256) stabK(const float* __restrict__ Kg,
                                             const float* __restrict__ Pg,
                                             unsigned* __restrict__ stab_ws){
  __shared__ float red[4];
  int tid=threadIdx.x, w=tid>>6, lane=tid&63, l15=lane&15, g=lane>>4;
  int fb=w*64;
  f16x8 pb[4][2];
  #pragma unroll
  for(int ft=0;ft<4;++ft)
    #pragma unroll
    for(int ks=0;ks<2;++ks){
      float x[8]; ld8(&Pg[(fb+16*ft+l15)*64+32*ks+8*g],x);
      #pragma unroll
      for(int i=0;i<8;++i) x[i]*=NRM;
      cvt8h(x,pb[ft][ks]);
    }
  float m=-3.4e38f;
  long base=(long)blockIdx.x*256;
  f32x4 zero={0.f,0.f,0.f,0.f};
  #pragma unroll 1
  for(int it=0;it<4;++it){
    long row0=base+it*64;
    f16x8 ka[4][2];
    #pragma unroll
    for(int rt=0;rt<4;++rt)
      #pragma unroll
      for(int ks=0;ks<2;++ks){
        float x[8]; ld8(&Kg[(row0+16*rt+l15)*64+32*ks+8*g],x);
        cvt8h(x,ka[rt][ks]);
      }
    f32x4 acc[4][4];
    #pragma unroll
    for(int rt=0;rt<4;++rt)
      #pragma unroll
      for(int ft=0;ft<4;++ft) acc[rt][ft]=zero;
    #pragma unroll
    for(int rt=0;rt<4;++rt)
      #pragma unroll
      for(int ft=0;ft<4;++ft)
        #pragma unroll
        for(int ks=0;ks<2;++ks)
          acc[rt][ft]=mfma16h(ka[rt][ks],pb[ft][ks],acc[rt][ft]);
    #pragma unroll
    for(int rt=0;rt<4;++rt)
      #pragma unroll
      for(int ft=0;ft<4;++ft)
        #pragma unroll
        for(int r=0;r<4;++r) m=fmaxf(m,acc[rt][ft][r]);
  }
  #pragma unroll
  for(int off=1;off<64;off<<=1) m=fmaxf(m,__shfl_xor(m,off));
  if(lane==0) red[w]=m;
  __syncthreads();
  if(tid==0){
    m=fmaxf(fmaxf(red[0],red[1]),fmaxf(red[2],red[3]));
    atomicMax(stab_ws,mapmax(m));
  }
}

// kp + ctx/ksum accumulation. grid = 512: 16 bh * 32 chunks of 256 rows,
// 8 iters. K LDS-staged dbuf; V reg-prefetched; P single bf16; 2-pass dd.
// Epilogue: mode=1 -> plain stores into private partial slice (bh,ch);
// mode=0 -> r13 atomic path.
__global__ void __launch_bounds__(256,2) ctxK(const float* __restrict__ Kg,
    const float* __restrict__ Vg, const float* __restrict__ Pg,
    const unsigned* __restrict__ stab_ws, float* __restrict__ ctx_g,
    float* __restrict__ ksum_g, float* __restrict__ part, int mode){
  __shared__ __align__(16) bf16 kpt_h[256*40];   // 20KB
  __shared__ float kstage[2][2048];              // 2 x 8KB staged K tiles
  int tid=threadIdx.x, w=tid>>6, lane=tid&63, l15=lane&15, g=lane>>4;
  int fb=w*64;
  int bh=blockIdx.x>>5, ch=blockIdx.x&31;
  long rowbase=(long)bh*N_ + ch*256;
  float stab=unmapmax(*stab_ws);
  bf16x8 pb[4][2];
  load_P_frags1(Pg,fb,l15,g,pb);
  f32x4 zero={0.f,0.f,0.f,0.f};
  f32x4 cacc[4][4];
  #pragma unroll
  for(int mt=0;mt<4;++mt)
    #pragma unroll
    for(int et=0;et<4;++et) cacc[mt][et]=zero;
  float ksacc[4]={0.f,0.f,0.f,0.f};
  int cur=0;
  STAGE32(Kg, &kstage[0][0], rowbase);
  __syncthreads();                       // drain staging for iter 0
  #pragma unroll 1
  for(int it=0;it<8;++it){
    long n0=rowbase+it*32;
    long np=(it==7)? rowbase : n0+32;    // last iter: dummy re-stage (harmless)
    STAGE32(Kg, &kstage[cur^1][0], np);  // issue next K tile; lands by barrier
    // V raw prefetch (latency hidden under dd-GEMM + exp)
    float vx[4][8];
    #pragma unroll
    for(int et=0;et<4;++et)
      #pragma unroll
      for(int j=0;j<8;++j) vx[et][j]=Vg[(n0+8*g+j)*64+16*et+l15];
    // K a-frags (split) + row sums of squares, from staged LDS
    bf16x8 ka_h[2][2], ka_l[2][2];
    float dsq[2];
    #pragma unroll
    for(int rt=0;rt<2;++rt){
      float ss=0.f;
      #pragma unroll
      for(int ks=0;ks<2;++ks){
        float x[8]; FRAGREAD(x,&kstage[cur][0],16*rt+l15,ks);
        #pragma unroll
        for(int i=0;i<8;++i) ss=fmaf(x[i],x[i],ss);
        split8(x,ka_h[rt][ks],ka_l[rt][ks]);
      }
      ss+=__shfl_xor(ss,16); ss+=__shfl_xor(ss,32);
      dsq[rt]=DSC*ss;
    }
    // dd = (Kh + Kl) @ P (2-pass; P single bf16)
    f32x4 dacc[2][4];
    #pragma unroll
    for(int rt=0;rt<2;++rt)
      #pragma unroll
      for(int ft=0;ft<4;++ft) dacc[rt][ft]=zero;
    #pragma unroll
    for(int rt=0;rt<2;++rt)
      #pragma unroll
      for(int ft=0;ft<4;++ft)
        #pragma unroll
        for(int ks=0;ks<2;++ks){
          dacc[rt][ft]=mfma16(ka_h[rt][ks],pb[ft][ks],dacc[rt][ft]);
          dacc[rt][ft]=mfma16(ka_l[rt][ks],pb[ft][ks],dacc[rt][ft]);
        }
    float dg[2][4];
    #pragma unroll
    for(int rt=0;rt<2;++rt)
      #pragma unroll
      for(int r=0;r<4;++r) dg[rt][r]=__shfl(dsq[rt],4*g+r);
    // kp = RATIO*exp(dd - diag - stab) + REPS, rounded to bf16;
    // ksum accumulates the SAME rounded value (consistent features).
    #pragma unroll
    for(int rt=0;rt<2;++rt)
      #pragma unroll
      for(int ft=0;ft<4;++ft){
        int f=fb+16*ft+l15;
        #pragma unroll
        for(int r=0;r<4;++r){
          float kp=fmaf(RATIO,__expf(dacc[rt][ft][r]-dg[rt][r]-stab),REPS);
          bf16 hb=(bf16)kp;
          ksacc[ft]+=(float)hb;
          int nn=16*rt+4*g+r;
          kpt_h[f*40+nn]=hb;
        }
      }
    // V b-frags (split from prefetched registers)
    bf16x8 vb_h[4], vb_l[4];
    #pragma unroll
    for(int et=0;et<4;++et) split8(vx[et],vb_h[et],vb_l[et]);
    // ctx += kp_b^T @ V (kp single-plane x V split = 2-pass)
    #pragma unroll
    for(int mt=0;mt<4;++mt){
      bf16x8 a_h=*(const bf16x8*)&kpt_h[(fb+16*mt+l15)*40+8*g];
      #pragma unroll
      for(int et=0;et<4;++et){
        cacc[mt][et]=mfma16(a_h,vb_h[et],cacc[mt][et]);
        cacc[mt][et]=mfma16(a_h,vb_l[et],cacc[mt][et]);
      }
    }
    __syncthreads();   // kstage[cur] reads done; staging vmcnt drained
    cur^=1;
  }
  // ---- ksum cross-g reduce (both modes) ----
  float ksred[4];
  #pragma unroll
  for(int ft=0;ft<4;++ft){
    float s=ksacc[ft];
    s+=__shfl_xor(s,16); s+=__shfl_xor(s,32);
    ksred[ft]=s;
  }
  if(mode){
    // private slice: no contention, plain stores, no init required
    float* cg=part+((long)ch*BH_+bh)*SLICE_W;
    #pragma unroll
    for(int mt=0;mt<4;++mt)
      #pragma unroll
      for(int et=0;et<4;++et)
        #pragma unroll
        for(int r=0;r<4;++r)
          cg[(fb+16*mt+4*g+r)*64+16*et+l15]=cacc[mt][et][r];
    if(g==0){
      #pragma unroll
      for(int ft=0;ft<4;++ft)
        cg[16384+fb+16*ft+l15]=ksred[ft];
    }
  }else{
    float* cg=ctx_g+(long)bh*16384;
    #pragma unroll
    for(int mt=0;mt<4;++mt)
      #pragma unroll
      for(int et=0;et<4;++et)
        #pragma unroll
        for(int r=0;r<4;++r)
          atomicAdd(&cg[(fb+16*mt+4*g+r)*64+16*et+l15],cacc[mt][et][r]);
    if(g==0){
      #pragma unroll
      for(int ft=0;ft<4;++ft)
        atomicAdd(&ksum_g[bh*256+fb+16*ft+l15],ksred[ft]);
    }
  }
}

// sum the 32 partial slices -> ctx / ksum. grid 520 x 256 (2 outputs/thread).
__global__ void __launch_bounds__(256) redK(const float* __restrict__ part,
    float* __restrict__ ctx_g, float* __restrict__ ksum_g){
  long t=(long)blockIdx.x*256+threadIdx.x;
  const long TOT=(long)BH_*SLICE_W;          // 266240
  for(long o=t;o<TOT;o+=(long)gridDim.x*256){
    int bh=(int)(o/SLICE_W), idx=(int)(o%SLICE_W);
    float s=0.f;
    #pragma unroll 8
    for(int ch=0;ch<32;++ch)
      s+=part[((long)ch*BH_+bh)*SLICE_W+idx];
    if(idx<16384) ctx_g[(long)bh*16384+idx]=s;
    else          ksum_g[bh*256+idx-16384]=s;
  }
}

// fused qp + out. grid = 512: 16 bh * 32 chunks of 256 rows, 8 iters.
// Q LDS-staged double-buffer; P single bf16 (2-pass dd); qp single-bf16
// direct ds_write_b16. UNCHANGED from round 13.
__global__ void __launch_bounds__(256,2) qoK(const float* __restrict__ Qg,
    const float* __restrict__ Pg, const float* __restrict__ ctx_g,
    const float* __restrict__ ksum_g, float* __restrict__ outg){
  __shared__ float qstage[2][2048];          // 2 x 8KB staged Q tiles (swizzled)
  __shared__ __align__(16) bf16 qpt[32*264]; // bf16 qp plane, [n][f], stride 264
  __shared__ float rmaxl[4][32];
  __shared__ float denl[4][32];
  int tid=threadIdx.x, w=tid>>6, lane=tid&63, l15=lane&15, g=lane>>4;
  int fb=w*64;
  int bh=blockIdx.x>>5, ch=blockIdx.x&31;
  long rowbase=(long)bh*N_ + ch*256;

  bf16x8 pb[4][2];
  load_P_frags1(Pg,fb,l15,g,pb);
  float ksv[4];
  #pragma unroll
  for(int ft=0;ft<4;++ft) ksv[ft]=ksum_g[bh*256+fb+16*ft+l15];
  // ctx b-frags for this wave's e-tile (et = w), split
  bf16x8 cb_h[8], cb_l[8];
  #pragma unroll
  for(int ks=0;ks<8;++ks){
    float x[8];
    #pragma unroll
    for(int j=0;j<8;++j) x[j]=ctx_g[(long)bh*16384+(32*ks+8*g+j)*64+16*w+l15];
    split8(x,cb_h[ks],cb_l[ks]);
  }
  f32x4 zero={0.f,0.f,0.f,0.f};
  int cur=0;
  STAGE32(Qg, &qstage[0][0], rowbase);
  __syncthreads();                     // drain staging for iter 0
  #pragma unroll 1
  for(int it=0;it<8;++it){
    long n0=rowbase+it*32;
    long np=(it==7)? rowbase : n0+32;  // last iter: dummy re-stage (harmless)
    STAGE32(Qg, &qstage[cur^1][0], np);// issue next tile; lands by next barrier
    // Q a-frags (split) + diag from staged LDS
    bf16x8 qa_h[2][2], qa_l[2][2];
    float dsq[2];
    #pragma unroll
    for(int rt=0;rt<2;++rt){
      float ss=0.f;
      #pragma unroll
      for(int ks=0;ks<2;++ks){
        float x[8]; FRAGREAD(x,&qstage[cur][0],16*rt+l15,ks);
        #pragma unroll
        for(int i=0;i<8;++i) ss=fmaf(x[i],x[i],ss);
        split8(x,qa_h[rt][ks],qa_l[rt][ks]);
      }
      ss+=__shfl_xor(ss,16); ss+=__shfl_xor(ss,32);
      dsq[rt]=DSC*ss;
    }
    // dd = (Qh + Ql) @ P (2-pass; P single bf16)
    f32x4 dacc[2][4];
    #pragma unroll
    for(int rt=0;rt<2;++rt)
      #pragma unroll
      for(int ft=0;ft<4;++ft) dacc[rt][ft]=zero;
    #pragma unroll
    for(int rt=0;rt<2;++rt)
      #pragma unroll
      for(int ft=0;ft<4;++ft)
        #pragma unroll
        for(int ks=0;ks<2;++ks){
          dacc[rt][ft]=mfma16(qa_h[rt][ks],pb[ft][ks],dacc[rt][ft]);
          dacc[rt][ft]=mfma16(qa_l[rt][ks],pb[ft][ks],dacc[rt][ft]);
        }
    float dg[2][4];
    #pragma unroll
    for(int rt=0;rt<2;++rt)
      #pragma unroll
      for(int r=0;r<4;++r) dg[rt][r]=__shfl(dsq[rt],4*g+r);
    // per-wave rowmax over its f-strip
    #pragma unroll
    for(int rt=0;rt<2;++rt)
      #pragma unroll
      for(int r=0;r<4;++r){
        float m=fmaxf(fmaxf(dacc[rt][0][r],dacc[rt][1][r]),
                      fmaxf(dacc[rt][2][r],dacc[rt][3][r]));
        m=fmaxf(m,__shfl_xor(m,1)); m=fmaxf(m,__shfl_xor(m,2));
        m=fmaxf(m,__shfl_xor(m,4)); m=fmaxf(m,__shfl_xor(m,8));
        if(l15==0) rmaxl[w][16*rt+4*g+r]=m;
      }
    __syncthreads();   // rowmax planes ready (also fences staging of cur^1)
    // qp (rounded bf16), den partials from the SAME rounded value,
    // direct b16 writes into qpt[n][f]
    #pragma unroll
    for(int rt=0;rt<2;++rt)
      #pragma unroll
      for(int r=0;r<4;++r){
        int nn=16*rt+4*g+r;
        float rm=fmaxf(fmaxf(rmaxl[0][nn],rmaxl[1][nn]),
                       fmaxf(rmaxl[2][nn],rmaxl[3][nn]));
        float dp=0.f;
        #pragma unroll
        for(int ft=0;ft<4;++ft){
          float qp=fmaf(RATIO,__expf(dacc[rt][ft][r]-dg[rt][r]-rm),REPS);
          bf16 hb=(bf16)qp;
          dp=fmaf((float)hb,ksv[ft],dp);
          qpt[nn*264 + fb+16*ft+l15]=hb;
        }
        dp+=__shfl_xor(dp,1); dp+=__shfl_xor(dp,2);
        dp+=__shfl_xor(dp,4); dp+=__shfl_xor(dp,8);
        if(l15==0) denl[w][nn]=dp;
      }
    __syncthreads();   // qpt + denl ready
    // out = qp_b @ ctx (single-plane qp x split ctx = 2-pass)
    f32x4 oacc[2]; oacc[0]=zero; oacc[1]=zero;
    #pragma unroll
    for(int ks=0;ks<8;++ks)
      #pragma unroll
      for(int mt=0;mt<2;++mt){
        bf16x8 a_h=*(const bf16x8*)&qpt[(16*mt+l15)*264+32*ks+8*g];
        oacc[mt]=mfma16(a_h,cb_h[ks],oacc[mt]);
        oacc[mt]=mfma16(a_h,cb_l[ks],oacc[mt]);
      }
    #pragma unroll
    for(int mt=0;mt<2;++mt)
      #pragma unroll
      for(int r=0;r<4;++r){
        int nn=16*mt+4*g+r;
        float den=denl[0][nn]+denl[1][nn]+denl[2][nn]+denl[3][nn];
        outg[(n0+nn)*64+16*w+l15]=oacc[mt][r]/den;
      }
    cur^=1;
  }
}

// ---------------- host ----------------

extern "C" void kernel_launch(void* const* d_in, const int* in_sizes, int n_in,
                              void* d_out, int out_size, void* d_ws, size_t ws_size,
                              hipStream_t stream) {
  (void)in_sizes; (void)n_in; (void)out_size;
  const float* q = (const float*)d_in[0];
  const float* k = (const float*)d_in[1];
  const float* v = (const float*)d_in[2];
  const float* P = (const float*)d_in[3];
  float* out = (float*)d_out;

  unsigned* stab = (unsigned*)d_ws;
  float* ctx  = (float*)d_ws + CTX_W;
  float* ksum = (float*)d_ws + KSUM_W;
  float* part = (float*)d_ws + PART_W;

  size_t need = ((size_t)PART_W + (size_t)32*BH_*SLICE_W) * 4;  // ~35.1 MB
  int mode = (ws_size >= need) ? 1 : 0;

  hipLaunchKernelGGL(initK, dim3(256), dim3(256), 0, stream, (unsigned*)d_ws);
  hipLaunchKernelGGL(stabK, dim3(512), dim3(256), 0, stream, k, P, stab);
  hipLaunchKernelGGL(ctxK, dim3(512), dim3(256), 0, stream, k, v, P, stab,
                     ctx, ksum, part, mode);
  if(mode)
    hipLaunchKernelGGL(redK, dim3(520), dim3(256), 0, stream, part, ctx, ksum);
  hipLaunchKernelGGL(qoK, dim3(512), dim3(256), 0, stream, q, P, ctx, ksum, out);
}